// Round 1
// baseline (1535.944 us; speedup 1.0000x reference)
//
#include <hip/hip_runtime.h>

// CommAgent fused pipeline for MI355X (gfx950), bf16 MFMA throughout.
// ROWS=65536, INPUT=512, H=256, NA=32, 4 comm steps, N_ACTIONS=16.

typedef __attribute__((ext_vector_type(8))) short frag8;   // 8 bf16 (4 VGPRs)
typedef __attribute__((ext_vector_type(4))) float facc4;   // MFMA C/D

__device__ __forceinline__ unsigned short f2bf(float f){
    unsigned u = __builtin_bit_cast(unsigned, f);
    u += 0x7fffu + ((u >> 16) & 1u);            // RNE
    return (unsigned short)(u >> 16);
}
__device__ __forceinline__ float bf2f(unsigned short h){
    unsigned u = ((unsigned)h) << 16;
    return __builtin_bit_cast(float, u);
}
__device__ __forceinline__ unsigned pk2(float a, float b){
    return (unsigned)f2bf(a) | ((unsigned)f2bf(b) << 16);
}
__device__ __forceinline__ float sigm(float x){ return 1.0f / (1.0f + __expf(-x)); }
__device__ __forceinline__ float tanh_(float x){ return 2.0f / (1.0f + __expf(-2.0f*x)) - 1.0f; }

__device__ __forceinline__ facc4 mfma16(frag8 a, frag8 b, facc4 c){
    return __builtin_amdgcn_mfma_f32_16x16x32_bf16(a, b, c, 0, 0, 0);
}
__device__ __forceinline__ void zacc(facc4* p, int n){
    #pragma unroll
    for (int i = 0; i < 16; ++i) { if (i < n) p[i] = (facc4){0.f,0.f,0.f,0.f}; }
}
// XOR-swizzled LDS index (16B-chunk granularity), ld in shorts (256 or 512)
__device__ __forceinline__ int swz(int row, int col, int ld){
    return row*ld + ((((col >> 3) ^ (row & 7)) << 3) | (col & 7));
}

// acc[NMB][4] += A_lds(rows mb0*16..) @ W[nbase+ncols, K]^T ; wave owns n-tiles 4w..4w+3
template<int NMB>
__device__ __forceinline__ void gemm_bt(facc4 acc[NMB][4],
    const unsigned short* __restrict__ Al, const int ld, const int mb0,
    const unsigned short* __restrict__ W, const int nbase, const int K, const int wK)
{
    const int lane = threadIdx.x & 63;
    const int wave = threadIdx.x >> 6;
    const int r16  = lane & 15;
    const int q8   = (lane >> 4) << 3;
    int rowbase[NMB], rx[NMB];
    #pragma unroll
    for (int mb = 0; mb < NMB; ++mb){
        int row = (mb0 + mb)*16 + r16;
        rowbase[mb] = row * ld;
        rx[mb] = row & 7;
    }
    const unsigned short* wbase = W + (size_t)(nbase + wave*64 + r16) * wK + q8;
    for (int k0 = 0; k0 < K; k0 += 32){
        const int c8 = (k0 + q8) >> 3;
        frag8 a[NMB];
        #pragma unroll
        for (int mb = 0; mb < NMB; ++mb)
            a[mb] = *(const frag8*)(Al + rowbase[mb] + ((c8 ^ rx[mb]) << 3));
        #pragma unroll
        for (int tt = 0; tt < 4; ++tt){
            frag8 b = *(const frag8*)(wbase + tt*16*wK + k0);
            #pragma unroll
            for (int mb = 0; mb < NMB; ++mb)
                acc[mb][tt] = mfma16(a[mb], b, acc[mb][tt]);
        }
    }
}

// ---- staging helpers: 64 rows x 256 cols into swizzled LDS (ld=256) ----
__device__ __forceinline__ void stage_bf16(unsigned short* dst, const unsigned short* src){
    int t = threadIdx.x;
    #pragma unroll
    for (int it = 0; it < 8; ++it){
        int idx = it*256 + t;             // 2048 chunks of 8 shorts
        int row = idx >> 5, ch = idx & 31;
        uint4 v = *(const uint4*)(src + (size_t)row*256 + (ch << 3));
        *(uint4*)(dst + row*256 + ((ch ^ (row & 7)) << 3)) = v;
    }
}
__device__ __forceinline__ void stage_f32(unsigned short* dst, const float* src){
    int t = threadIdx.x;
    #pragma unroll
    for (int it = 0; it < 8; ++it){
        int idx = it*256 + t;
        int row = idx >> 5, ch = idx & 31;
        const float4* s = (const float4*)(src + (size_t)row*256 + (ch << 3));
        float4 a = s[0], b = s[1];
        uint4 o; o.x = pk2(a.x,a.y); o.y = pk2(a.z,a.w); o.z = pk2(b.x,b.y); o.w = pk2(b.z,b.w);
        *(uint4*)(dst + row*256 + ((ch ^ (row & 7)) << 3)) = o;
    }
}

// ---- weight f32->bf16 conversion (segments packed contiguously in ws) ----
__global__ void k_prep(const float* __restrict__ s0, const float* __restrict__ s1,
                       const float* __restrict__ s2, const float* __restrict__ s3,
                       const float* __restrict__ s4, const float* __restrict__ s5,
                       unsigned short* __restrict__ dst)
{
    int idx = (blockIdx.x*256 + threadIdx.x) * 4;   // 921600 elems total
    const float* src;
    if      (idx < 131072) src = s0 + idx;
    else if (idx < 327680) src = s1 + (idx - 131072);
    else if (idx < 524288) src = s2 + (idx - 327680);
    else if (idx < 720896) src = s3 + (idx - 524288);
    else if (idx < 917504) src = s4 + (idx - 720896);
    else                   src = s5 + (idx - 917504);
    float4 v = *(const float4*)src;
    uint2 o; o.x = pk2(v.x, v.y); o.y = pk2(v.z, v.w);
    *(uint2*)(dst + idx) = o;
}

// ---- x = relu(inputs @ W1^T + b1); also extract neighbor matrix + 1/n ----
__global__ __launch_bounds__(256,2) void k_x(const float* __restrict__ inputs,
    const unsigned short* __restrict__ W1c, const float* __restrict__ b1,
    unsigned short* __restrict__ Xout, unsigned short* __restrict__ NB,
    float* __restrict__ invn)
{
    __shared__ unsigned short Al[64*512];   // 64 KB, swizzled, ld=512
    const int base = blockIdx.x * 64;
    {
        const float* src = inputs + (size_t)base * 512;
        int t = threadIdx.x;
        #pragma unroll
        for (int it = 0; it < 16; ++it){
            int idx = it*256 + t;            // 4096 chunks
            int row = idx >> 6, ch = idx & 63;
            const float4* s = (const float4*)(src + (size_t)row*512 + (ch << 3));
            float4 a = s[0], c = s[1];
            uint4 o; o.x = pk2(a.x,a.y); o.y = pk2(a.z,a.w); o.z = pk2(c.x,c.y); o.w = pk2(c.z,c.w);
            *(uint4*)(Al + row*512 + ((ch ^ (row & 7)) << 3)) = o;
        }
    }
    __syncthreads();
    // neighbor extraction: cols 260+8k, k=0..30; row agent i = global_row & 31
    if (threadIdx.x < 64){
        int row = threadIdx.x;
        int gr = base + row;
        int i = gr & 31;
        int rx = row & 7;
        unsigned short* nbrow = NB + (size_t)gr * 32;
        float s = 0.f;
        nbrow[i] = 0;
        #pragma unroll
        for (int k = 0; k < 31; ++k){
            // col = 260+8k -> chunk 32+k, sub-offset 4
            unsigned short v = Al[row*512 + ((((32 + k) ^ rx) << 3) | 4)];
            s += bf2f(v);
            nbrow[k + (k >= i)] = v;
        }
        invn[gr] = 1.0f / s;
    }
    facc4 acc[4][4];
    zacc(&acc[0][0], 16);
    gemm_bt<4>(acc, Al, 512, 0, W1c, 0, 512, 512);
    const int lane = threadIdx.x & 63, wave = threadIdx.x >> 6;
    const int r16 = lane & 15, q4 = (lane >> 4) << 2;
    #pragma unroll
    for (int tt = 0; tt < 4; ++tt){
        int col = wave*64 + tt*16 + r16;
        float bias = b1[col];
        #pragma unroll
        for (int mb = 0; mb < 4; ++mb){
            #pragma unroll
            for (int k = 0; k < 4; ++k){
                float v = acc[mb][tt][k] + bias;
                v = fmaxf(v, 0.f);
                Xout[(size_t)(base + mb*16 + q4 + k)*256 + col] = f2bf(v);
            }
        }
    }
}

// ---- GRU core: gi = giA@Wih^T, gh = ghA@Whh^T, out = (1-z)*n + z*ghA ----
template<bool WRITE_F32>
__device__ __forceinline__ void gru_core(
    const unsigned short* giA, const unsigned short* ghA,   // LDS, ld=256 swizzled
    const unsigned short* __restrict__ Wih, const unsigned short* __restrict__ Whh,
    const float* __restrict__ bih, const float* __restrict__ bhh,
    int base, float* __restrict__ out32, unsigned short* __restrict__ out16)
{
    const int lane = threadIdx.x & 63, wave = threadIdx.x >> 6;
    const int r16 = lane & 15, q4 = (lane >> 4) << 2;
    facc4 acc[4][4];
    unsigned rp[4][4][2], zp[4][4][2];
    // phase r
    zacc(&acc[0][0], 16);
    gemm_bt<4>(acc, giA, 256, 0, Wih, 0, 256, 256);
    gemm_bt<4>(acc, ghA, 256, 0, Whh, 0, 256, 256);
    #pragma unroll
    for (int tt = 0; tt < 4; ++tt){
        int col = wave*64 + tt*16 + r16;
        float bs = bih[col] + bhh[col];
        #pragma unroll
        for (int mb = 0; mb < 4; ++mb){
            rp[mb][tt][0] = pk2(sigm(acc[mb][tt][0]+bs), sigm(acc[mb][tt][1]+bs));
            rp[mb][tt][1] = pk2(sigm(acc[mb][tt][2]+bs), sigm(acc[mb][tt][3]+bs));
        }
    }
    // phase z
    zacc(&acc[0][0], 16);
    gemm_bt<4>(acc, giA, 256, 0, Wih, 256, 256, 256);
    gemm_bt<4>(acc, ghA, 256, 0, Whh, 256, 256, 256);
    #pragma unroll
    for (int tt = 0; tt < 4; ++tt){
        int col = wave*64 + tt*16 + r16;
        float bs = bih[256+col] + bhh[256+col];
        #pragma unroll
        for (int mb = 0; mb < 4; ++mb){
            zp[mb][tt][0] = pk2(sigm(acc[mb][tt][0]+bs), sigm(acc[mb][tt][1]+bs));
            zp[mb][tt][1] = pk2(sigm(acc[mb][tt][2]+bs), sigm(acc[mb][tt][3]+bs));
        }
    }
    // phase n + epilogue, split over m-block halves to bound VGPRs
    #pragma unroll
    for (int mbh = 0; mbh < 2; ++mbh){
        facc4 ai[2][4], ah[2][4];
        zacc(&ai[0][0], 8);
        zacc(&ah[0][0], 8);
        gemm_bt<2>(ai, giA, 256, mbh*2, Wih, 512, 256, 256);
        gemm_bt<2>(ah, ghA, 256, mbh*2, Whh, 512, 256, 256);
        #pragma unroll
        for (int tt = 0; tt < 4; ++tt){
            int col = wave*64 + tt*16 + r16;
            float bi = bih[512+col], bh = bhh[512+col];
            #pragma unroll
            for (int m2 = 0; m2 < 2; ++m2){
                int mb = mbh*2 + m2;
                #pragma unroll
                for (int k = 0; k < 4; ++k){
                    int rloc = mb*16 + q4 + k;
                    float iv = ai[m2][tt][k] + bi;
                    float hv = ah[m2][tt][k] + bh;
                    float r = bf2f((unsigned short)(rp[mb][tt][k>>1] >> ((k&1)*16)));
                    float z = bf2f((unsigned short)(zp[mb][tt][k>>1] >> ((k&1)*16)));
                    float n = tanh_(iv + r*hv);
                    float hp = bf2f(ghA[swz(rloc, col, 256)]);
                    float h = (1.f - z)*n + z*hp;
                    size_t g = (size_t)(base + rloc)*256 + col;
                    if (WRITE_F32) out32[g] = h;
                    out16[g] = f2bf(h);
                }
            }
        }
    }
}

__global__ __launch_bounds__(256,2) void k_rnn(const unsigned short* __restrict__ X,
    const float* __restrict__ h0, const unsigned short* __restrict__ Wih,
    const unsigned short* __restrict__ Whh, const float* __restrict__ bih,
    const float* __restrict__ bhh, float* __restrict__ hrnn,
    unsigned short* __restrict__ hout)
{
    __shared__ unsigned short Xl[64*256];
    __shared__ unsigned short Hl[64*256];
    const int base = blockIdx.x * 64;
    stage_bf16(Xl, X + (size_t)base*256);
    stage_f32 (Hl, h0 + (size_t)base*256);
    __syncthreads();
    gru_core<true>(Xl, Hl, Wih, Whh, bih, bhh, base, hrnn, hout);
}

__global__ __launch_bounds__(256,2) void k_comm(const unsigned short* __restrict__ hin,
    const unsigned short* __restrict__ NB, const float* __restrict__ invn,
    const unsigned short* __restrict__ Wih, const unsigned short* __restrict__ Whh,
    const float* __restrict__ bih, const float* __restrict__ bhh,
    unsigned short* __restrict__ hout)
{
    __shared__ unsigned short Hl[64*256];
    __shared__ unsigned short Cl[64*256];
    const int base = blockIdx.x * 64;   // 2 agent-groups of 32
    stage_bf16(Hl, hin + (size_t)base*256);
    __syncthreads();
    const int lane = threadIdx.x & 63, wave = threadIdx.x >> 6;
    const int r16 = lane & 15, q8 = (lane >> 4) << 3, q4 = (lane >> 4) << 2;
    // c = NB @ h per group (M=64 over 2 groups, N=256, K=32), A from global NB
    facc4 acc[4][4];
    zacc(&acc[0][0], 16);
    frag8 a[4];
    #pragma unroll
    for (int mb = 0; mb < 4; ++mb)
        a[mb] = *(const frag8*)(NB + (size_t)(base + mb*16 + r16)*32 + q8);
    #pragma unroll
    for (int tt = 0; tt < 4; ++tt){
        int col = wave*64 + tt*16 + r16;
        int cc = col >> 3, c7 = col & 7;
        union { frag8 v; unsigned short u[8]; } b0, b1;
        #pragma unroll
        for (int j = 0; j < 8; ++j){
            int k0r = q8 + j;          // group 0 rows 0..31
            int k1r = 32 + q8 + j;     // group 1 rows 32..63
            b0.u[j] = Hl[k0r*256 + (((cc ^ (k0r & 7)) << 3) | c7)];
            b1.u[j] = Hl[k1r*256 + (((cc ^ (k1r & 7)) << 3) | c7)];
        }
        acc[0][tt] = mfma16(a[0], b0.v, acc[0][tt]);
        acc[1][tt] = mfma16(a[1], b0.v, acc[1][tt]);
        acc[2][tt] = mfma16(a[2], b1.v, acc[2][tt]);
        acc[3][tt] = mfma16(a[3], b1.v, acc[3][tt]);
    }
    #pragma unroll
    for (int mb = 0; mb < 4; ++mb){
        #pragma unroll
        for (int k = 0; k < 4; ++k){
            int rloc = mb*16 + q4 + k;
            float inv = invn[base + rloc];
            #pragma unroll
            for (int tt = 0; tt < 4; ++tt){
                int col = wave*64 + tt*16 + r16;
                Cl[rloc*256 + (((( col >> 3) ^ (rloc & 7)) << 3) | (col & 7))]
                    = f2bf(acc[mb][tt][k] * inv);
            }
        }
    }
    __syncthreads();
    gru_core<false>(Hl, Cl, Wih, Whh, bih, bhh, base, nullptr, hout);
}

// ---- q = h @ W2^T + b2 (N=16 => one MFMA n-tile, wave per 16-row block) ----
__global__ __launch_bounds__(256) void k_q(const unsigned short* __restrict__ h,
    const unsigned short* __restrict__ W2c, const float* __restrict__ b2,
    float* __restrict__ q)
{
    const int base = blockIdx.x * 64;
    const int lane = threadIdx.x & 63, wave = threadIdx.x >> 6;
    const int r16 = lane & 15, q8 = (lane >> 4) << 3, q4 = (lane >> 4) << 2;
    facc4 acc = (facc4){0.f,0.f,0.f,0.f};
    const unsigned short* arow = h + (size_t)(base + wave*16 + r16)*256 + q8;
    const unsigned short* brow = W2c + (size_t)r16*256 + q8;
    #pragma unroll
    for (int k0 = 0; k0 < 256; k0 += 32){
        frag8 a = *(const frag8*)(arow + k0);
        frag8 b = *(const frag8*)(brow + k0);
        acc = mfma16(a, b, acc);
    }
    float bias = b2[r16];
    #pragma unroll
    for (int k = 0; k < 4; ++k){
        int row = base + wave*16 + q4 + k;
        q[(size_t)row*16 + r16] = acc[k] + bias;
    }
}

extern "C" void kernel_launch(void* const* d_in, const int* in_sizes, int n_in,
                              void* d_out, int out_size, void* d_ws, size_t ws_size,
                              hipStream_t stream)
{
    const float* inputs = (const float*)d_in[0];
    const float* h0     = (const float*)d_in[1];
    const float* W1     = (const float*)d_in[2];
    const float* b1     = (const float*)d_in[3];
    const float* rWih   = (const float*)d_in[4];
    const float* rWhh   = (const float*)d_in[5];
    const float* rbih   = (const float*)d_in[6];
    const float* rbhh   = (const float*)d_in[7];
    const float* cWih   = (const float*)d_in[8];
    const float* cWhh   = (const float*)d_in[9];
    const float* cbih   = (const float*)d_in[10];
    const float* cbhh   = (const float*)d_in[11];
    const float* W2     = (const float*)d_in[12];
    const float* b2     = (const float*)d_in[13];

    float* qout = (float*)d_out;                    // 65536 x 16
    float* hrnn = qout + (size_t)65536*16;          // 65536 x 256

    // ws layout (bf16 elems): weights 921600 | hA 16777216 | hB/X 16777216 | NB 2097152 | invn(f32)
    unsigned short* wsb  = (unsigned short*)d_ws;
    unsigned short* W1c   = wsb;
    unsigned short* rWihc = wsb + 131072;
    unsigned short* rWhhc = wsb + 327680;
    unsigned short* cWihc = wsb + 524288;
    unsigned short* cWhhc = wsb + 720896;
    unsigned short* W2c   = wsb + 917504;
    unsigned short* hA    = wsb + 921600;
    unsigned short* hB    = hA + (size_t)16777216;  // also X buffer (dead after k_rnn)
    unsigned short* Xbuf  = hB;
    unsigned short* NB    = hB + (size_t)16777216;
    float* invn = (float*)(NB + (size_t)2097152);

    dim3 blk(256);
    k_prep<<<900, blk, 0, stream>>>(W1, rWih, rWhh, cWih, cWhh, W2, wsb);
    k_x   <<<1024, blk, 0, stream>>>(inputs, W1c, b1, Xbuf, NB, invn);
    k_rnn <<<1024, blk, 0, stream>>>(Xbuf, h0, rWihc, rWhhc, rbih, rbhh, hrnn, hA);
    k_comm<<<1024, blk, 0, stream>>>(hA, NB, invn, cWihc, cWhhc, cbih, cbhh, hB);
    k_comm<<<1024, blk, 0, stream>>>(hB, NB, invn, cWihc, cWhhc, cbih, cbhh, hA);
    k_comm<<<1024, blk, 0, stream>>>(hA, NB, invn, cWihc, cWhhc, cbih, cbhh, hB);
    k_comm<<<1024, blk, 0, stream>>>(hB, NB, invn, cWihc, cWhhc, cbih, cbhh, hA);
    k_q   <<<1024, blk, 0, stream>>>(hA, W2c, b2, qout);
}